// Round 3
// baseline (525.133 us; speedup 1.0000x reference)
//
#include <hip/hip_runtime.h>

typedef unsigned short u16;
typedef __attribute__((ext_vector_type(8))) short bf16x8;
typedef __attribute__((ext_vector_type(4))) float f32x4;

#define NT 256
#define BT 64
#define A1S 152   // elems; 76 words/row, 16B-aligned rows, ~2-way bank aliasing (free)
#define A2S 136   // elems; 68 words/row, 16B-aligned rows, ~2-way bank aliasing (free)

__device__ __forceinline__ float bu2f(u16 v) { return __uint_as_float(((unsigned)v) << 16); }
__device__ __forceinline__ u16 f2bu(float f) {
  unsigned u = __float_as_uint(f);
  u += 0x7FFF + ((u >> 16) & 1);
  return (u16)(u >> 16);
}
__device__ __forceinline__ float sigm(float x) { return 1.0f / (1.0f + __expf(-x)); }
__device__ __forceinline__ float tanh_(float x) {
  float ax = fabsf(x);
  float e = __expf(-2.0f * ax);
  float t = (1.0f - e) / (1.0f + e);
  return copysignf(t, x);
}
__device__ __forceinline__ uint2 pack4(float4 v) {
  return make_uint2((unsigned)f2bu(v.x) | ((unsigned)f2bu(v.y) << 16),
                    (unsigned)f2bu(v.z) | ((unsigned)f2bu(v.w) << 16));
}
__device__ __forceinline__ bf16x8 ldw8(const float* p) {
  float4 a = *(const float4*)p;
  float4 b = *(const float4*)(p + 4);
  bf16x8 r;
  r[0] = (short)f2bu(a.x); r[1] = (short)f2bu(a.y); r[2] = (short)f2bu(a.z); r[3] = (short)f2bu(a.w);
  r[4] = (short)f2bu(b.x); r[5] = (short)f2bu(b.y); r[6] = (short)f2bu(b.z); r[7] = (short)f2bu(b.w);
  return r;
}

// fp32 scalar region offsets (floats)
#define O_DW   0
#define O_PWW  9
#define O_PWB  25
#define O_S1DW 41
#define O_S1PW 89
#define O_S1PB 345
#define O_S2DW 361
#define O_S2PW 409
#define O_S2PB 665
#define O_B1   681
#define O_B2   937
#define O_FC1B 1193
#define O_FC2W 1225
#define O_FC2B 1257
// 1258 floats = 5032 B -> 5056

#define R_A1 5056                    // 19456 B: A1[64][152] bf16 ; zz[64*33] f32 aliases after P7
#define R_A2 (R_A1 + 19456)          // 17408 B: A2[64][136] bf16 ; y0_h[32*40] bf16 aliases during conv
#define R_CT (R_A2 + 17408)          // 11264 B: xs_h[32*123] bf16 / u1_h[32*11*16] bf16 (time-shared)
#define SMEM_TOTAL (R_CT + 11264)    // 53184 B -> 3 blocks/CU

__global__ __launch_bounds__(NT, 3) void tenvad(
    const float* __restrict__ xg,
    const float* __restrict__ h1g, const float* __restrict__ c1g,
    const float* __restrict__ h2g, const float* __restrict__ c2g,
    const float* __restrict__ dwWg, const float* __restrict__ pwWg, const float* __restrict__ pwBg,
    const float* __restrict__ s1dwg, const float* __restrict__ s1pwg, const float* __restrict__ s1pbg,
    const float* __restrict__ s2dwg, const float* __restrict__ s2pwg, const float* __restrict__ s2pbg,
    const float* __restrict__ wih1, const float* __restrict__ whh1,
    const float* __restrict__ bih1, const float* __restrict__ bhh1,
    const float* __restrict__ wih2, const float* __restrict__ whh2,
    const float* __restrict__ bih2, const float* __restrict__ bhh2,
    const float* __restrict__ fc1wg, const float* __restrict__ fc1bg,
    const float* __restrict__ fc2wg, const float* __restrict__ fc2bg,
    float* __restrict__ out, int B)
{
  __shared__ __align__(16) unsigned char smem[SMEM_TOTAL];
  const int t = threadIdx.x;
  const int blk = blockIdx.x;
  const int base = blk * BT;

  float* sw = (float*)smem;
  u16* A1   = (u16*)(smem + R_A1);
  float* zz = (float*)(smem + R_A1);
  u16* A2   = (u16*)(smem + R_A2);
  u16* y0   = (u16*)(smem + R_A2);   // conv-phase alias (2560 B)
  u16* xs   = (u16*)(smem + R_CT);
  u16* u1   = (u16*)(smem + R_CT);

  float* probO = out;
  float* h1o = out + B;
  float* c1o = out + B + B * 64;
  float* h2o = out + B + B * 128;
  float* c2o = out + B + B * 192;

  // ---- P0: weights/biases -> LDS fp32; P1: h1 -> A1 cols 80..143 ----
  for (int i = t; i < 9;   i += NT) sw[O_DW  +i] = dwWg[i];
  for (int i = t; i < 16;  i += NT) sw[O_PWW +i] = pwWg[i];
  for (int i = t; i < 16;  i += NT) sw[O_PWB +i] = pwBg[i];
  for (int i = t; i < 48;  i += NT) sw[O_S1DW+i] = s1dwg[i];
  for (int i = t; i < 256; i += NT) sw[O_S1PW+i] = s1pwg[i];
  for (int i = t; i < 16;  i += NT) sw[O_S1PB+i] = s1pbg[i];
  for (int i = t; i < 48;  i += NT) sw[O_S2DW+i] = s2dwg[i];
  for (int i = t; i < 256; i += NT) sw[O_S2PW+i] = s2pwg[i];
  for (int i = t; i < 16;  i += NT) sw[O_S2PB+i] = s2pbg[i];
  for (int i = t; i < 256; i += NT) sw[O_B1+i] = bih1[i] + bhh1[i];
  for (int i = t; i < 256; i += NT) sw[O_B2+i] = bih2[i] + bhh2[i];
  for (int i = t; i < 32;  i += NT) sw[O_FC1B+i] = fc1bg[i];
  for (int i = t; i < 32;  i += NT) sw[O_FC2W+i] = fc2wg[i];
  if (t == 0) sw[O_FC2B] = fc2bg[0];
  {
    const float4* hsrc = (const float4*)h1g + (size_t)blk * 1024;
    for (int i = t; i < 1024; i += NT) {
      int m = i >> 4, j4 = (i & 15) * 4;
      *(uint2*)(A1 + m * A1S + 80 + j4) = pack4(hsrc[i]);
    }
  }

  // ---- conv stack, two half-tiles of 32 rows ----
#pragma unroll 1
  for (int p = 0; p < 2; ++p) {
    // stage xs half-tile (32*123 fp32 -> bf16)
    {
      const float4* src = (const float4*)(xg + (size_t)(base + p * 32) * 123);
      for (int i = t; i < 984; i += NT) *(uint2*)(xs + i * 4) = pack4(src[i]);
    }
    __syncthreads();
    // depthwise 3x3 -> y0 bf16 [32][40] (w<39 valid)
    for (int i = t; i < 1280; i += NT) {
      int b = i / 40, w = i - b * 40;
      if (w < 39) {
        const u16* xb = xs + b * 123;
        float s = 0.f;
#pragma unroll
        for (int kh = 0; kh < 3; ++kh)
#pragma unroll
          for (int kw = 0; kw < 3; ++kw)
            s = fmaf(bu2f(xb[kh * 41 + w + kw]), sw[O_DW + kh * 3 + kw], s);
        y0[b * 40 + w] = f2bu(s);
      }
    }
    __syncthreads();
    // fused pw+relu+maxpool+sep1dw+pw+relu -> u1 [32][11][16] (col 10 = zero pad)
    for (int i = t; i < 352; i += NT) {
      int b = i / 11, qq = i - b * 11;
      u16* dst = u1 + (b * 11 + qq) * 16;
      if (qq == 10) {
#pragma unroll
        for (int c = 0; c < 16; ++c) dst[c] = 0;
      } else {
        float t1[16];
#pragma unroll
        for (int c = 0; c < 16; ++c) t1[c] = 0.f;
#pragma unroll
        for (int k = 0; k < 3; ++k) {
          int w = 2 * qq - 1 + k;
          if (w >= 0 && w < 19) {
            float a0 = bu2f(y0[b * 40 + 2 * w]);
            float a1 = bu2f(y0[b * 40 + 2 * w + 1]);
            float a2 = bu2f(y0[b * 40 + 2 * w + 2]);
            float mx = fmaxf(a0, fmaxf(a1, a2));
            float mn = fminf(a0, fminf(a1, a2));
#pragma unroll
            for (int c = 0; c < 16; ++c) {
              float wv = sw[O_PWW + c];
              float pc = fmaxf(fmaf(wv, (wv > 0.f ? mx : mn), sw[O_PWB + c]), 0.f);
              t1[c] = fmaf(pc, sw[O_S1DW + c * 3 + k], t1[c]);
            }
          }
        }
#pragma unroll
        for (int co = 0; co < 16; ++co) {
          float s = sw[O_S1PB + co];
#pragma unroll
          for (int ci = 0; ci < 16; ++ci) s = fmaf(t1[ci], sw[O_S1PW + co * 16 + ci], s);
          dst[co] = f2bu(fmaxf(s, 0.f));
        }
      }
    }
    __syncthreads();
    // sep2 dw(stride2)+pw+relu -> feat into A1 rows [32p..32p+32), cols 0..79
    for (int i = t; i < 160; i += NT) {
      int b = i / 5, r = i - b * 5;
      float v[16];
#pragma unroll
      for (int c = 0; c < 16; ++c) v[c] = 0.f;
#pragma unroll
      for (int k = 0; k < 3; ++k) {
        const u16* ur = u1 + (b * 11 + 2 * r + k) * 16;
#pragma unroll
        for (int c = 0; c < 16; ++c) v[c] = fmaf(bu2f(ur[c]), sw[O_S2DW + c * 3 + k], v[c]);
      }
      u16* dst = A1 + (p * 32 + b) * A1S + r * 16;
#pragma unroll
      for (int co = 0; co < 16; ++co) {
        float s = sw[O_S2PB + co];
#pragma unroll
        for (int ci = 0; ci < 16; ++ci) s = fmaf(v[ci], sw[O_S2PW + co * 16 + ci], s);
        dst[co] = f2bu(fmaxf(s, 0.f));
      }
    }
    __syncthreads();
  }

  // ---- P6: h2 -> A2 cols 64..127 (y0 alias now dead) ----
  {
    const float4* hsrc = (const float4*)h2g + (size_t)blk * 1024;
    for (int i = t; i < 1024; i += NT) {
      int m = i >> 4, j4 = (i & 15) * 4;
      *(uint2*)(A2 + m * A2S + 64 + j4) = pack4(hsrc[i]);
    }
  }
  __syncthreads();

  const int w = t >> 6, lane = t & 63, q = lane >> 4, l15 = lane & 15;
  const int j = w * 16 + l15;

  // ---- P7: gates1 = [feat|h1] @ [wih1|whh1]^T (K=144), cell1 ----
  {
    f32x4 acc[4][4];
#pragma unroll
    for (int mt = 0; mt < 4; ++mt)
#pragma unroll
      for (int g = 0; g < 4; ++g) { acc[mt][g][0]=0.f; acc[mt][g][1]=0.f; acc[mt][g][2]=0.f; acc[mt][g][3]=0.f; }

    const float* rowIh[4]; const float* rowHh[4];
#pragma unroll
    for (int g = 0; g < 4; ++g) {
      int n = g * 64 + j;
      rowIh[g] = wih1 + n * 80;
      rowHh[g] = whh1 + n * 64;
    }
    const u16* aBase[4];
#pragma unroll
    for (int mt = 0; mt < 4; ++mt) aBase[mt] = A1 + (mt * 16 + l15) * A1S + q * 8;

#pragma unroll
    for (int kc = 0; kc < 5; ++kc) {
      int k0 = kc * 32;
      bf16x8 af[4], bfm[4];
#pragma unroll
      for (int mt = 0; mt < 4; ++mt) {
        if (kc < 4) af[mt] = *(const bf16x8*)(aBase[mt] + k0);
        else {
          bf16x8 zv = {};
          if (q < 2) zv = *(const bf16x8*)(aBase[mt] + 128);
          af[mt] = zv;
        }
      }
#pragma unroll
      for (int g = 0; g < 4; ++g) {
        if (kc == 0)      bfm[g] = ldw8(rowIh[g] + q * 8);
        else if (kc == 1) bfm[g] = ldw8(rowIh[g] + 32 + q * 8);
        else if (kc == 2) {
          const float* pp = (q < 2) ? (rowIh[g] + 64 + q * 8) : (rowHh[g] + (q - 2) * 8);
          bfm[g] = ldw8(pp);
        }
        else if (kc == 3) bfm[g] = ldw8(rowHh[g] + 16 + q * 8);
        else {
          bf16x8 zv = {};
          if (q < 2) zv = ldw8(rowHh[g] + 48 + q * 8);
          bfm[g] = zv;
        }
      }
#pragma unroll
      for (int mt = 0; mt < 4; ++mt)
#pragma unroll
        for (int g = 0; g < 4; ++g)
          acc[mt][g] = __builtin_amdgcn_mfma_f32_16x16x32_bf16(af[mt], bfm[g], acc[mt][g], 0, 0, 0);
    }

    float bI = sw[O_B1 + j], bF = sw[O_B1 + 64 + j], bG = sw[O_B1 + 128 + j], bO = sw[O_B1 + 192 + j];
#pragma unroll
    for (int mt = 0; mt < 4; ++mt) {
#pragma unroll
      for (int r = 0; r < 4; ++r) {
        int m = mt * 16 + q * 4 + r;
        int b = base + m;
        float iv = acc[mt][0][r] + bI;
        float fv = acc[mt][1][r] + bF;
        float gv = acc[mt][2][r] + bG;
        float ov = acc[mt][3][r] + bO;
        float cold = c1g[b * 64 + j];
        float cn = sigm(fv) * cold + sigm(iv) * tanh_(gv);
        float hn = sigm(ov) * tanh_(cn);
        c1o[b * 64 + j] = cn;
        h1o[b * 64 + j] = hn;
        A2[m * A2S + j] = f2bu(hn);   // lstm2 input cols 0..63
      }
    }
  }
  __syncthreads();

  // ---- P8: gates2 = [h1_new|h2_old] @ [wih2|whh2]^T (K=128), cell2 ----
  {
    f32x4 acc[4][4];
#pragma unroll
    for (int mt = 0; mt < 4; ++mt)
#pragma unroll
      for (int g = 0; g < 4; ++g) { acc[mt][g][0]=0.f; acc[mt][g][1]=0.f; acc[mt][g][2]=0.f; acc[mt][g][3]=0.f; }

    const float* rowIh[4]; const float* rowHh[4];
#pragma unroll
    for (int g = 0; g < 4; ++g) {
      int n = g * 64 + j;
      rowIh[g] = wih2 + n * 64;
      rowHh[g] = whh2 + n * 64;
    }
    const u16* aBase[4];
#pragma unroll
    for (int mt = 0; mt < 4; ++mt) aBase[mt] = A2 + (mt * 16 + l15) * A2S + q * 8;

#pragma unroll
    for (int kc = 0; kc < 4; ++kc) {
      int k0 = kc * 32;
      bf16x8 af[4], bfm[4];
#pragma unroll
      for (int mt = 0; mt < 4; ++mt) af[mt] = *(const bf16x8*)(aBase[mt] + k0);
#pragma unroll
      for (int g = 0; g < 4; ++g) {
        if (kc == 0)      bfm[g] = ldw8(rowIh[g] + q * 8);
        else if (kc == 1) bfm[g] = ldw8(rowIh[g] + 32 + q * 8);
        else if (kc == 2) bfm[g] = ldw8(rowHh[g] + q * 8);
        else              bfm[g] = ldw8(rowHh[g] + 32 + q * 8);
      }
#pragma unroll
      for (int mt = 0; mt < 4; ++mt)
#pragma unroll
        for (int g = 0; g < 4; ++g)
          acc[mt][g] = __builtin_amdgcn_mfma_f32_16x16x32_bf16(af[mt], bfm[g], acc[mt][g], 0, 0, 0);
    }
    __syncthreads();  // all reads of h2_old done before overwrite below

    float bI = sw[O_B2 + j], bF = sw[O_B2 + 64 + j], bG = sw[O_B2 + 128 + j], bO = sw[O_B2 + 192 + j];
#pragma unroll
    for (int mt = 0; mt < 4; ++mt) {
#pragma unroll
      for (int r = 0; r < 4; ++r) {
        int m = mt * 16 + q * 4 + r;
        int b = base + m;
        float iv = acc[mt][0][r] + bI;
        float fv = acc[mt][1][r] + bF;
        float gv = acc[mt][2][r] + bG;
        float ov = acc[mt][3][r] + bO;
        float cold = c2g[b * 64 + j];
        float cn = sigm(fv) * cold + sigm(iv) * tanh_(gv);
        float hn = sigm(ov) * tanh_(cn);
        c2o[b * 64 + j] = cn;
        h2o[b * 64 + j] = hn;
        A2[m * A2S + 64 + j] = f2bu(hn);  // A2 now holds [h1_new | h2_new]
      }
    }
  }
  __syncthreads();

  // ---- P9: fc1 on z=[h2,h1]: our A2=[h1|h2] with weight K-cols remapped ----
  {
    f32x4 accf[2];
#pragma unroll
    for (int nt = 0; nt < 2; ++nt) { accf[nt][0]=0.f; accf[nt][1]=0.f; accf[nt][2]=0.f; accf[nt][3]=0.f; }
    int m0 = w * 16;
#pragma unroll
    for (int kc = 0; kc < 4; ++kc) {
      int k0 = kc * 32;
      int refk0 = (kc & 2) ? (kc - 2) * 32 : 64 + kc * 32;
      bf16x8 a = *(const bf16x8*)(A2 + (m0 + l15) * A2S + k0 + q * 8);
#pragma unroll
      for (int nt = 0; nt < 2; ++nt) {
        int n = nt * 16 + l15;
        bf16x8 bfr = ldw8(fc1wg + n * 128 + refk0 + q * 8);
        accf[nt] = __builtin_amdgcn_mfma_f32_16x16x32_bf16(a, bfr, accf[nt], 0, 0, 0);
      }
    }
#pragma unroll
    for (int nt = 0; nt < 2; ++nt) {
      int n = nt * 16 + l15;
#pragma unroll
      for (int r = 0; r < 4; ++r) {
        int m = m0 + q * 4 + r;
        zz[m * 33 + n] = fmaxf(accf[nt][r] + sw[O_FC1B + n], 0.f);
      }
    }
  }
  __syncthreads();

  // ---- P10: fc2 + sigmoid ----
  if (t < 64) {
    int m = t;
    float s = sw[O_FC2B];
#pragma unroll
    for (int k = 0; k < 32; ++k) s = fmaf(zz[m * 33 + k], sw[O_FC2W + k], s);
    probO[base + m] = sigm(s);
  }
}

extern "C" void kernel_launch(void* const* d_in, const int* in_sizes, int n_in,
                              void* d_out, int out_size, void* d_ws, size_t ws_size,
                              hipStream_t stream) {
  (void)n_in; (void)out_size; (void)d_ws; (void)ws_size;
  int B = in_sizes[0] / 123;
  dim3 grid(B / BT), block(NT);
  hipLaunchKernelGGL(tenvad, grid, block, 0, stream,
      (const float*)d_in[0], (const float*)d_in[1], (const float*)d_in[2],
      (const float*)d_in[3], (const float*)d_in[4],
      (const float*)d_in[5], (const float*)d_in[6], (const float*)d_in[7],
      (const float*)d_in[8], (const float*)d_in[9], (const float*)d_in[10],
      (const float*)d_in[11], (const float*)d_in[12], (const float*)d_in[13],
      (const float*)d_in[14], (const float*)d_in[15], (const float*)d_in[16], (const float*)d_in[17],
      (const float*)d_in[18], (const float*)d_in[19], (const float*)d_in[20], (const float*)d_in[21],
      (const float*)d_in[22], (const float*)d_in[23], (const float*)d_in[24], (const float*)d_in[25],
      (float*)d_out, B);
}

// Round 4
// 365.381 us; speedup vs baseline: 1.4372x; 1.4372x over previous
//
#include <hip/hip_runtime.h>

typedef unsigned short u16;
typedef __attribute__((ext_vector_type(8))) short bf16x8;
typedef __attribute__((ext_vector_type(4))) float f32x4;

#define NT 256
#define BT 64
#define A1S 152   // row stride (elems); 16B-aligned rows
#define A2S 136

__device__ __forceinline__ float bu2f(u16 v) { return __uint_as_float(((unsigned)v) << 16); }
__device__ __forceinline__ u16 f2bu(float f) {
  unsigned u = __float_as_uint(f);
  u += 0x7FFF + ((u >> 16) & 1);
  return (u16)(u >> 16);
}
__device__ __forceinline__ float sigm(float x) { return 1.0f / (1.0f + __expf(-x)); }
__device__ __forceinline__ float tanh_(float x) {
  float ax = fabsf(x);
  float e = __expf(-2.0f * ax);
  float t = (1.0f - e) / (1.0f + e);
  return copysignf(t, x);
}
__device__ __forceinline__ uint2 pack4(float4 v) {
  return make_uint2((unsigned)f2bu(v.x) | ((unsigned)f2bu(v.y) << 16),
                    (unsigned)f2bu(v.z) | ((unsigned)f2bu(v.w) << 16));
}

// d_ws layout (u16 elems): wih1[256*80] | whh1[256*64] | wih2[256*64] | whh2[256*64] | fc1(K-remapped)[32*128]
#define WS_WIH1 0
#define WS_WHH1 20480
#define WS_WIH2 36864
#define WS_WHH2 53248
#define WS_FC1  69632
#define WS_NW   73728            // u16 count
#define WS_BOFF (WS_NW * 2)      // 147456 B, then f32: b1[256], b2[256]

__global__ __launch_bounds__(NT) void prep(
    const float* __restrict__ wih1, const float* __restrict__ whh1,
    const float* __restrict__ wih2, const float* __restrict__ whh2,
    const float* __restrict__ fc1w,
    const float* __restrict__ bih1, const float* __restrict__ bhh1,
    const float* __restrict__ bih2, const float* __restrict__ bhh2,
    u16* __restrict__ wbf, float* __restrict__ bc)
{
  int i = blockIdx.x * NT + threadIdx.x;
  if (i < 20480)       wbf[i] = f2bu(wih1[i]);
  else if (i < 36864)  wbf[i] = f2bu(whh1[i - 20480]);
  else if (i < 53248)  wbf[i] = f2bu(wih2[i - 36864]);
  else if (i < 69632)  wbf[i] = f2bu(whh2[i - 53248]);
  else if (i < 73728) {
    int l = i - 69632, n = l >> 7, k = l & 127;
    int ks = (k < 64) ? k + 64 : k - 64;   // z=[h2|h1] vs our A2=[h1|h2]
    wbf[i] = f2bu(fc1w[n * 128 + ks]);
  }
  if (i < 256)      bc[i] = bih1[i] + bhh1[i];
  else if (i < 512) bc[i] = bih2[i - 256] + bhh2[i - 256];
}

// fp32 scalar LDS offsets (floats)
#define O_DW   0
#define O_PWW  9
#define O_PWB  25
#define O_S1DW 41
#define O_S1PW 89
#define O_S1PB 345
#define O_S2DW 361
#define O_S2PW 409
#define O_S2PB 665
#define O_B1   681
#define O_B2   937
#define O_FC1B 1193
#define O_FC2W 1225
#define O_FC2B 1257

#define R_A1 5056                    // 19456 B: A1[64][152] bf16 ; zz f32 aliases after P7
#define R_A2 (R_A1 + 19456)          // 17408 B: A2[64][136] bf16 ; y0 aliases during conv
#define R_CT (R_A2 + 17408)          // 11264 B: xs / u1 (time-shared)
#define SMEM_TOTAL (R_CT + 11264)    // 53184 B -> 3 blocks/CU by LDS

__global__ __launch_bounds__(NT) void tenvad(
    const float* __restrict__ xg,
    const float* __restrict__ h1g, const float* __restrict__ c1g,
    const float* __restrict__ h2g, const float* __restrict__ c2g,
    const float* __restrict__ dwWg, const float* __restrict__ pwWg, const float* __restrict__ pwBg,
    const float* __restrict__ s1dwg, const float* __restrict__ s1pwg, const float* __restrict__ s1pbg,
    const float* __restrict__ s2dwg, const float* __restrict__ s2pwg, const float* __restrict__ s2pbg,
    const float* __restrict__ fc1bg, const float* __restrict__ fc2wg, const float* __restrict__ fc2bg,
    const u16* __restrict__ wbf, const float* __restrict__ bc,
    float* __restrict__ out, int B)
{
  __shared__ __align__(16) unsigned char smem[SMEM_TOTAL];
  const int t = threadIdx.x;
  const int blk = blockIdx.x;
  const int base = blk * BT;

  float* sw = (float*)smem;
  u16* A1   = (u16*)(smem + R_A1);
  float* zz = (float*)(smem + R_A1);
  u16* A2   = (u16*)(smem + R_A2);
  u16* y0   = (u16*)(smem + R_A2);
  u16* xs   = (u16*)(smem + R_CT);
  u16* u1   = (u16*)(smem + R_CT);

  float* probO = out;
  float* h1o = out + B;
  float* c1o = out + B + B * 64;
  float* h2o = out + B + B * 128;
  float* c2o = out + B + B * 192;

  const u16* wIh1 = wbf + WS_WIH1;   // [256][80]
  const u16* wHh1 = wbf + WS_WHH1;   // [256][64]
  const u16* wIh2 = wbf + WS_WIH2;
  const u16* wHh2 = wbf + WS_WHH2;
  const u16* wFc1 = wbf + WS_FC1;    // [32][128] K-remapped

  // ---- P0: small params -> LDS; h1 -> A1 cols 80..143 ----
  for (int i = t; i < 9;   i += NT) sw[O_DW  +i] = dwWg[i];
  for (int i = t; i < 16;  i += NT) sw[O_PWW +i] = pwWg[i];
  for (int i = t; i < 16;  i += NT) sw[O_PWB +i] = pwBg[i];
  for (int i = t; i < 48;  i += NT) sw[O_S1DW+i] = s1dwg[i];
  for (int i = t; i < 256; i += NT) sw[O_S1PW+i] = s1pwg[i];
  for (int i = t; i < 16;  i += NT) sw[O_S1PB+i] = s1pbg[i];
  for (int i = t; i < 48;  i += NT) sw[O_S2DW+i] = s2dwg[i];
  for (int i = t; i < 256; i += NT) sw[O_S2PW+i] = s2pwg[i];
  for (int i = t; i < 16;  i += NT) sw[O_S2PB+i] = s2pbg[i];
  for (int i = t; i < 512; i += NT) sw[O_B1+i] = bc[i];      // b1 then b2 contiguous
  for (int i = t; i < 32;  i += NT) sw[O_FC1B+i] = fc1bg[i];
  for (int i = t; i < 32;  i += NT) sw[O_FC2W+i] = fc2wg[i];
  if (t == 0) sw[O_FC2B] = fc2bg[0];
  {
    const float4* hsrc = (const float4*)h1g + (size_t)blk * 1024;
    for (int i = t; i < 1024; i += NT) {
      int m = i >> 4, j4 = (i & 15) * 4;
      *(uint2*)(A1 + m * A1S + 80 + j4) = pack4(hsrc[i]);
    }
  }

  // ---- conv stack, two half-tiles of 32 rows ----
#pragma unroll 1
  for (int p = 0; p < 2; ++p) {
    {
      const float4* src = (const float4*)(xg + (size_t)(base + p * 32) * 123);
      for (int i = t; i < 984; i += NT) *(uint2*)(xs + i * 4) = pack4(src[i]);
    }
    __syncthreads();
    for (int i = t; i < 1280; i += NT) {
      int b = i / 40, w = i - b * 40;
      if (w < 39) {
        const u16* xb = xs + b * 123;
        float s = 0.f;
#pragma unroll
        for (int kh = 0; kh < 3; ++kh)
#pragma unroll
          for (int kw = 0; kw < 3; ++kw)
            s = fmaf(bu2f(xb[kh * 41 + w + kw]), sw[O_DW + kh * 3 + kw], s);
        y0[b * 40 + w] = f2bu(s);
      }
    }
    __syncthreads();
    for (int i = t; i < 352; i += NT) {
      int b = i / 11, qq = i - b * 11;
      u16* dst = u1 + (b * 11 + qq) * 16;
      if (qq == 10) {
#pragma unroll
        for (int c = 0; c < 16; ++c) dst[c] = 0;
      } else {
        float t1[16];
#pragma unroll
        for (int c = 0; c < 16; ++c) t1[c] = 0.f;
#pragma unroll
        for (int k = 0; k < 3; ++k) {
          int w = 2 * qq - 1 + k;
          if (w >= 0 && w < 19) {
            float a0 = bu2f(y0[b * 40 + 2 * w]);
            float a1 = bu2f(y0[b * 40 + 2 * w + 1]);
            float a2 = bu2f(y0[b * 40 + 2 * w + 2]);
            float mx = fmaxf(a0, fmaxf(a1, a2));
            float mn = fminf(a0, fminf(a1, a2));
#pragma unroll
            for (int c = 0; c < 16; ++c) {
              float wv = sw[O_PWW + c];
              float pc = fmaxf(fmaf(wv, (wv > 0.f ? mx : mn), sw[O_PWB + c]), 0.f);
              t1[c] = fmaf(pc, sw[O_S1DW + c * 3 + k], t1[c]);
            }
          }
        }
#pragma unroll
        for (int co = 0; co < 16; ++co) {
          float s = sw[O_S1PB + co];
#pragma unroll
          for (int ci = 0; ci < 16; ++ci) s = fmaf(t1[ci], sw[O_S1PW + co * 16 + ci], s);
          dst[co] = f2bu(fmaxf(s, 0.f));
        }
      }
    }
    __syncthreads();
    for (int i = t; i < 160; i += NT) {
      int b = i / 5, r = i - b * 5;
      float v[16];
#pragma unroll
      for (int c = 0; c < 16; ++c) v[c] = 0.f;
#pragma unroll
      for (int k = 0; k < 3; ++k) {
        const u16* ur = u1 + (b * 11 + 2 * r + k) * 16;
#pragma unroll
        for (int c = 0; c < 16; ++c) v[c] = fmaf(bu2f(ur[c]), sw[O_S2DW + c * 3 + k], v[c]);
      }
      u16* dst = A1 + (p * 32 + b) * A1S + r * 16;
#pragma unroll
      for (int co = 0; co < 16; ++co) {
        float s = sw[O_S2PB + co];
#pragma unroll
        for (int ci = 0; ci < 16; ++ci) s = fmaf(v[ci], sw[O_S2PW + co * 16 + ci], s);
        dst[co] = f2bu(fmaxf(s, 0.f));
      }
    }
    __syncthreads();
  }

  // ---- P6: h2 -> A2 cols 64..127 ----
  {
    const float4* hsrc = (const float4*)h2g + (size_t)blk * 1024;
    for (int i = t; i < 1024; i += NT) {
      int m = i >> 4, j4 = (i & 15) * 4;
      *(uint2*)(A2 + m * A2S + 64 + j4) = pack4(hsrc[i]);
    }
  }
  __syncthreads();

  const int w = t >> 6, lane = t & 63, q = lane >> 4, l15 = lane & 15;
  const int j = w * 16 + l15;

  // ---- P7: gates1 (K=144), cell1 ; split over M to halve acc pressure ----
#pragma unroll 1
  for (int mh = 0; mh < 2; ++mh) {
    f32x4 acc[2][4];
#pragma unroll
    for (int mt = 0; mt < 2; ++mt)
#pragma unroll
      for (int g = 0; g < 4; ++g) { acc[mt][g][0]=0.f; acc[mt][g][1]=0.f; acc[mt][g][2]=0.f; acc[mt][g][3]=0.f; }

    const u16* aB0 = A1 + (mh * 32 + l15) * A1S + q * 8;
    const u16* aB1 = aB0 + 16 * A1S;

#pragma unroll
    for (int kc = 0; kc < 5; ++kc) {
      bf16x8 af0, af1, bfm[4];
      if (kc < 4) {
        af0 = *(const bf16x8*)(aB0 + kc * 32);
        af1 = *(const bf16x8*)(aB1 + kc * 32);
      } else {
        bf16x8 z = {};
        af0 = z; af1 = z;
        if (q < 2) { af0 = *(const bf16x8*)(aB0 + 128); af1 = *(const bf16x8*)(aB1 + 128); }
      }
#pragma unroll
      for (int g = 0; g < 4; ++g) {
        int n = g * 64 + j;
        if (kc == 0)      bfm[g] = *(const bf16x8*)(wIh1 + n * 80 + q * 8);
        else if (kc == 1) bfm[g] = *(const bf16x8*)(wIh1 + n * 80 + 32 + q * 8);
        else if (kc == 2) bfm[g] = (q < 2) ? *(const bf16x8*)(wIh1 + n * 80 + 64 + q * 8)
                                           : *(const bf16x8*)(wHh1 + n * 64 + (q - 2) * 8);
        else if (kc == 3) bfm[g] = *(const bf16x8*)(wHh1 + n * 64 + 16 + q * 8);
        else {
          bf16x8 z = {};
          if (q < 2) z = *(const bf16x8*)(wHh1 + n * 64 + 48 + q * 8);
          bfm[g] = z;
        }
      }
#pragma unroll
      for (int g = 0; g < 4; ++g) {
        acc[0][g] = __builtin_amdgcn_mfma_f32_16x16x32_bf16(af0, bfm[g], acc[0][g], 0, 0, 0);
        acc[1][g] = __builtin_amdgcn_mfma_f32_16x16x32_bf16(af1, bfm[g], acc[1][g], 0, 0, 0);
      }
    }

    float bI = sw[O_B1 + j], bF = sw[O_B1 + 64 + j], bG = sw[O_B1 + 128 + j], bO = sw[O_B1 + 192 + j];
#pragma unroll
    for (int mt = 0; mt < 2; ++mt) {
#pragma unroll
      for (int r = 0; r < 4; ++r) {
        int m = mh * 32 + mt * 16 + q * 4 + r;
        int b = base + m;
        float iv = acc[mt][0][r] + bI;
        float fv = acc[mt][1][r] + bF;
        float gv = acc[mt][2][r] + bG;
        float ov = acc[mt][3][r] + bO;
        float cold = c1g[b * 64 + j];
        float cn = sigm(fv) * cold + sigm(iv) * tanh_(gv);
        float hn = sigm(ov) * tanh_(cn);
        c1o[b * 64 + j] = cn;
        h1o[b * 64 + j] = hn;
        A2[m * A2S + j] = f2bu(hn);   // cols 0..63; not read until P8
      }
    }
  }
  __syncthreads();

  // ---- P8: gates2 (K=128), cell2 ; split over M, defer A2 h2_new writes ----
  unsigned h2p[8];   // 16 bf16 packed
#pragma unroll 1
  for (int mh = 0; mh < 2; ++mh) {
    f32x4 acc[2][4];
#pragma unroll
    for (int mt = 0; mt < 2; ++mt)
#pragma unroll
      for (int g = 0; g < 4; ++g) { acc[mt][g][0]=0.f; acc[mt][g][1]=0.f; acc[mt][g][2]=0.f; acc[mt][g][3]=0.f; }

    const u16* aB0 = A2 + (mh * 32 + l15) * A2S + q * 8;
    const u16* aB1 = aB0 + 16 * A2S;

#pragma unroll
    for (int kc = 0; kc < 4; ++kc) {
      bf16x8 af0 = *(const bf16x8*)(aB0 + kc * 32);
      bf16x8 af1 = *(const bf16x8*)(aB1 + kc * 32);
      bf16x8 bfm[4];
#pragma unroll
      for (int g = 0; g < 4; ++g) {
        int n = g * 64 + j;
        if (kc == 0)      bfm[g] = *(const bf16x8*)(wIh2 + n * 64 + q * 8);
        else if (kc == 1) bfm[g] = *(const bf16x8*)(wIh2 + n * 64 + 32 + q * 8);
        else if (kc == 2) bfm[g] = *(const bf16x8*)(wHh2 + n * 64 + q * 8);
        else              bfm[g] = *(const bf16x8*)(wHh2 + n * 64 + 32 + q * 8);
      }
#pragma unroll
      for (int g = 0; g < 4; ++g) {
        acc[0][g] = __builtin_amdgcn_mfma_f32_16x16x32_bf16(af0, bfm[g], acc[0][g], 0, 0, 0);
        acc[1][g] = __builtin_amdgcn_mfma_f32_16x16x32_bf16(af1, bfm[g], acc[1][g], 0, 0, 0);
      }
    }

    float bI = sw[O_B2 + j], bF = sw[O_B2 + 64 + j], bG = sw[O_B2 + 128 + j], bO = sw[O_B2 + 192 + j];
#pragma unroll
    for (int mt = 0; mt < 2; ++mt) {
#pragma unroll
      for (int r = 0; r < 4; ++r) {
        int m = mh * 32 + mt * 16 + q * 4 + r;
        int b = base + m;
        float iv = acc[mt][0][r] + bI;
        float fv = acc[mt][1][r] + bF;
        float gv = acc[mt][2][r] + bG;
        float ov = acc[mt][3][r] + bO;
        float cold = c2g[b * 64 + j];
        float cn = sigm(fv) * cold + sigm(iv) * tanh_(gv);
        float hn = sigm(ov) * tanh_(cn);
        c2o[b * 64 + j] = cn;
        h2o[b * 64 + j] = hn;
        int idx = mh * 8 + mt * 4 + r;
        unsigned hb = (unsigned)f2bu(hn);
        if (idx & 1) h2p[idx >> 1] |= hb << 16; else h2p[idx >> 1] = hb;
      }
    }
  }
  __syncthreads();   // all reads of h2_old complete grid-block-wide
#pragma unroll
  for (int idx = 0; idx < 16; ++idx) {
    int m = (idx >> 3) * 32 + ((idx >> 2) & 1) * 16 + q * 4 + (idx & 3);
    A2[m * A2S + 64 + j] = (u16)(h2p[idx >> 1] >> ((idx & 1) * 16));
  }
  __syncthreads();

  // ---- P9: fc1 on A2=[h1|h2] with pre-remapped weights ----
  {
    f32x4 accf[2];
#pragma unroll
    for (int nt = 0; nt < 2; ++nt) { accf[nt][0]=0.f; accf[nt][1]=0.f; accf[nt][2]=0.f; accf[nt][3]=0.f; }
    int m0 = w * 16;
#pragma unroll
    for (int kc = 0; kc < 4; ++kc) {
      int k0 = kc * 32;
      bf16x8 a = *(const bf16x8*)(A2 + (m0 + l15) * A2S + k0 + q * 8);
#pragma unroll
      for (int nt = 0; nt < 2; ++nt) {
        int n = nt * 16 + l15;
        bf16x8 bfr = *(const bf16x8*)(wFc1 + n * 128 + k0 + q * 8);
        accf[nt] = __builtin_amdgcn_mfma_f32_16x16x32_bf16(a, bfr, accf[nt], 0, 0, 0);
      }
    }
#pragma unroll
    for (int nt = 0; nt < 2; ++nt) {
      int n = nt * 16 + l15;
#pragma unroll
      for (int r = 0; r < 4; ++r) {
        int m = m0 + q * 4 + r;
        zz[m * 33 + n] = fmaxf(accf[nt][r] + sw[O_FC1B + n], 0.f);
      }
    }
  }
  __syncthreads();

  // ---- P10: fc2 + sigmoid ----
  if (t < 64) {
    int m = t;
    float s = sw[O_FC2B];
#pragma unroll
    for (int k = 0; k < 32; ++k) s = fmaf(zz[m * 33 + k], sw[O_FC2W + k], s);
    probO[base + m] = sigm(s);
  }
}

extern "C" void kernel_launch(void* const* d_in, const int* in_sizes, int n_in,
                              void* d_out, int out_size, void* d_ws, size_t ws_size,
                              hipStream_t stream) {
  (void)n_in; (void)out_size; (void)ws_size;
  int B = in_sizes[0] / 123;
  u16* wbf = (u16*)d_ws;
  float* bcm = (float*)((char*)d_ws + WS_BOFF);

  hipLaunchKernelGGL(prep, dim3(288), dim3(NT), 0, stream,
      (const float*)d_in[14], (const float*)d_in[15],
      (const float*)d_in[18], (const float*)d_in[19],
      (const float*)d_in[22],
      (const float*)d_in[16], (const float*)d_in[17],
      (const float*)d_in[20], (const float*)d_in[21],
      wbf, bcm);

  hipLaunchKernelGGL(tenvad, dim3(B / BT), dim3(NT), 0, stream,
      (const float*)d_in[0], (const float*)d_in[1], (const float*)d_in[2],
      (const float*)d_in[3], (const float*)d_in[4],
      (const float*)d_in[5], (const float*)d_in[6], (const float*)d_in[7],
      (const float*)d_in[8], (const float*)d_in[9], (const float*)d_in[10],
      (const float*)d_in[11], (const float*)d_in[12], (const float*)d_in[13],
      (const float*)d_in[23], (const float*)d_in[24], (const float*)d_in[25],
      wbf, bcm,
      (float*)d_out, B);
}

// Round 5
// 316.383 us; speedup vs baseline: 1.6598x; 1.1549x over previous
//
#include <hip/hip_runtime.h>

typedef unsigned short u16;
typedef __attribute__((ext_vector_type(8))) short bf16x8;
typedef __attribute__((ext_vector_type(4))) float f32x4;

#define NT 256
#define BT 64
#define A1S 160   // lstm A1 row stride (elems): feat 0..79 | h1 80..143 | zero 144..159
#define A2S 136   // lstm A2 row stride: h1new 0..63 | h2 64..127 | pad

__device__ __forceinline__ float bu2f(u16 v) { return __uint_as_float(((unsigned)v) << 16); }
__device__ __forceinline__ u16 f2bu(float f) {
  unsigned u = __float_as_uint(f);
  u += 0x7FFF + ((u >> 16) & 1);
  return (u16)(u >> 16);
}
__device__ __forceinline__ float sigm(float x) { return 1.0f / (1.0f + __expf(-x)); }
__device__ __forceinline__ float tanh_(float x) {
  float ax = fabsf(x);
  float e = __expf(-2.0f * ax);
  float t = (1.0f - e) / (1.0f + e);
  return copysignf(t, x);
}
__device__ __forceinline__ uint2 pack4(float4 v) {
  return make_uint2((unsigned)f2bu(v.x) | ((unsigned)f2bu(v.y) << 16),
                    (unsigned)f2bu(v.z) | ((unsigned)f2bu(v.w) << 16));
}

// ---- d_ws layout ----
// u16: w1cat[256][160] | w2cat[256][128] | fc1(K-remapped)[32][128]   = 77824 u16
// then f32 bc[512] at byte 155648; then feat[B][80] u16 at byte 157696
#define WS_W1   0
#define WS_W2   40960
#define WS_FC1  73728
#define WS_BOFF 155648
#define WS_FEAT_U16 78848

__global__ __launch_bounds__(NT) void prep(
    const float* __restrict__ wih1, const float* __restrict__ whh1,
    const float* __restrict__ wih2, const float* __restrict__ whh2,
    const float* __restrict__ fc1w,
    const float* __restrict__ bih1, const float* __restrict__ bhh1,
    const float* __restrict__ bih2, const float* __restrict__ bhh2,
    u16* __restrict__ wbf, float* __restrict__ bc)
{
  int i = blockIdx.x * NT + threadIdx.x;
  if (i < 40960) {                         // w1cat[n][160] = [wih1 | whh1 | 0]
    int n = i / 160, k = i - n * 160;
    float v = 0.f;
    if (k < 80) v = wih1[n * 80 + k];
    else if (k < 144) v = whh1[n * 64 + (k - 80)];
    wbf[i] = f2bu(v);
  } else if (i < 73728) {                  // w2cat[n][128] = [wih2 | whh2]
    int l = i - 40960, n = l >> 7, k = l & 127;
    float v = (k < 64) ? wih2[n * 64 + k] : whh2[n * 64 + (k - 64)];
    wbf[i] = f2bu(v);
  } else if (i < 77824) {                  // fc1 with K halves swapped (z=[h2|h1] -> ours [h1|h2])
    int l = i - 73728, n = l >> 7, k = l & 127;
    int ks = (k < 64) ? k + 64 : k - 64;
    wbf[i] = f2bu(fc1w[n * 128 + ks]);
  }
  if (i < 256)      bc[i] = bih1[i] + bhh1[i];
  else if (i < 512) bc[i] = bih2[i - 256] + bhh2[i - 256];
}

// ================= conv kernel =================
// fp32 param LDS offsets (floats)
#define O_DW   0
#define O_PWW  9
#define O_PWB  25
#define O_S1DW 41
#define O_S1PW 89
#define O_S1PB 345
#define O_S2DW 361
#define O_S2PW 409
#define O_S2PB 665
// 681 floats -> 2752 B
#define CR_X 2752                    // xs[64*123] 15744 B / u1[64*11*16] 22528 B (time-shared, max)
#define CR_Y (CR_X + 22528)          // y0[64*40] bf16 5120 B
#define CSMEM (CR_Y + 5120)          // 30400 B

__global__ __launch_bounds__(NT) void convk(
    const float* __restrict__ xg,
    const float* __restrict__ dwWg, const float* __restrict__ pwWg, const float* __restrict__ pwBg,
    const float* __restrict__ s1dwg, const float* __restrict__ s1pwg, const float* __restrict__ s1pbg,
    const float* __restrict__ s2dwg, const float* __restrict__ s2pwg, const float* __restrict__ s2pbg,
    u16* __restrict__ featg)
{
  __shared__ __align__(16) unsigned char smem[CSMEM];
  const int t = threadIdx.x;
  const int blk = blockIdx.x;
  const int base = blk * BT;

  float* sw = (float*)smem;
  u16* xs = (u16*)(smem + CR_X);
  u16* u1 = (u16*)(smem + CR_X);
  u16* y0 = (u16*)(smem + CR_Y);

  for (int i = t; i < 9;   i += NT) sw[O_DW  +i] = dwWg[i];
  for (int i = t; i < 16;  i += NT) sw[O_PWW +i] = pwWg[i];
  for (int i = t; i < 16;  i += NT) sw[O_PWB +i] = pwBg[i];
  for (int i = t; i < 48;  i += NT) sw[O_S1DW+i] = s1dwg[i];
  for (int i = t; i < 256; i += NT) sw[O_S1PW+i] = s1pwg[i];
  for (int i = t; i < 16;  i += NT) sw[O_S1PB+i] = s1pbg[i];
  for (int i = t; i < 48;  i += NT) sw[O_S2DW+i] = s2dwg[i];
  for (int i = t; i < 256; i += NT) sw[O_S2PW+i] = s2pwg[i];
  for (int i = t; i < 16;  i += NT) sw[O_S2PB+i] = s2pbg[i];
  {
    const float4* src = (const float4*)xg + (size_t)blk * 1968;
    for (int i = t; i < 1968; i += NT) *(uint2*)(xs + i * 4) = pack4(src[i]);
  }
  __syncthreads();

  // depthwise 3x3 -> y0 bf16 [64][40]
  for (int i = t; i < 2560; i += NT) {
    int b = i / 40, w = i - b * 40;
    if (w < 39) {
      const u16* xb = xs + b * 123;
      float s = 0.f;
#pragma unroll
      for (int kh = 0; kh < 3; ++kh)
#pragma unroll
        for (int kw = 0; kw < 3; ++kw)
          s = fmaf(bu2f(xb[kh * 41 + w + kw]), sw[O_DW + kh * 3 + kw], s);
      y0[b * 40 + w] = f2bu(s);
    }
  }
  __syncthreads();

  // fused pw+relu+maxpool+sep1dw+pw+relu -> u1 [64][11][16] (col 10 zero); overwrites xs region
  for (int i = t; i < 704; i += NT) {
    int b = i / 11, qq = i - b * 11;
    u16* dst = u1 + (b * 11 + qq) * 16;
    if (qq == 10) {
#pragma unroll
      for (int c = 0; c < 16; ++c) dst[c] = 0;
    } else {
      float t1[16];
#pragma unroll
      for (int c = 0; c < 16; ++c) t1[c] = 0.f;
#pragma unroll
      for (int k = 0; k < 3; ++k) {
        int w = 2 * qq - 1 + k;
        if (w >= 0 && w < 19) {
          float a0 = bu2f(y0[b * 40 + 2 * w]);
          float a1 = bu2f(y0[b * 40 + 2 * w + 1]);
          float a2 = bu2f(y0[b * 40 + 2 * w + 2]);
          float mx = fmaxf(a0, fmaxf(a1, a2));
          float mn = fminf(a0, fminf(a1, a2));
#pragma unroll
          for (int c = 0; c < 16; ++c) {
            float wv = sw[O_PWW + c];
            float pc = fmaxf(fmaf(wv, (wv > 0.f ? mx : mn), sw[O_PWB + c]), 0.f);
            t1[c] = fmaf(pc, sw[O_S1DW + c * 3 + k], t1[c]);
          }
        }
      }
#pragma unroll
      for (int co = 0; co < 16; ++co) {
        float s = sw[O_S1PB + co];
#pragma unroll
        for (int ci = 0; ci < 16; ++ci) s = fmaf(t1[ci], sw[O_S1PW + co * 16 + ci], s);
        dst[co] = f2bu(fmaxf(s, 0.f));
      }
    }
  }
  __syncthreads();

  // sep2 dw(stride2)+pw+relu -> feat[B][80] bf16 in ws
  for (int i = t; i < 320; i += NT) {
    int b = i / 5, r = i - b * 5;
    float v[16];
#pragma unroll
    for (int c = 0; c < 16; ++c) v[c] = 0.f;
#pragma unroll
    for (int k = 0; k < 3; ++k) {
      const u16* ur = u1 + (b * 11 + 2 * r + k) * 16;
#pragma unroll
      for (int c = 0; c < 16; ++c) v[c] = fmaf(bu2f(ur[c]), sw[O_S2DW + c * 3 + k], v[c]);
    }
    u16* dst = featg + (size_t)(base + b) * 80 + r * 16;
#pragma unroll
    for (int co = 0; co < 16; ++co) {
      float s = sw[O_S2PB + co];
#pragma unroll
      for (int ci = 0; ci < 16; ++ci) s = fmaf(v[ci], sw[O_S2PW + co * 16 + ci], s);
      dst[co] = f2bu(fmaxf(s, 0.f));
    }
  }
}

// ================= lstm + fc kernel =================
// LDS: sw[577 f32] (b1 0..255 | b2 256..511 | fc1b 512..543 | fc2w 544..575 | fc2b 576) -> 2560 B
#define LO_B1   0
#define LO_B2   256
#define LO_FC1B 512
#define LO_FC2W 544
#define LO_FC2B 576
#define LR_A1 2560                    // A1[64][160] bf16 = 20480 B ; h2new cols 0..63 after P8; zz f32 aliases last
#define LR_A2 (LR_A1 + 20480)         // A2[64][136] bf16 = 17408 B
#define LSMEM (LR_A2 + 17408)         // 40448 B

__global__ __launch_bounds__(NT) void lstmk(
    const float* __restrict__ h1g, const float* __restrict__ c1g,
    const float* __restrict__ h2g, const float* __restrict__ c2g,
    const float* __restrict__ fc1bg, const float* __restrict__ fc2wg, const float* __restrict__ fc2bg,
    const u16* __restrict__ wbf, const float* __restrict__ bc, const u16* __restrict__ featg,
    float* __restrict__ out, int B)
{
  __shared__ __align__(16) unsigned char smem[LSMEM];
  const int t = threadIdx.x;
  const int blk = blockIdx.x;
  const int base = blk * BT;

  float* sw = (float*)smem;
  u16* A1 = (u16*)(smem + LR_A1);
  float* zz = (float*)(smem + LR_A1);
  u16* A2 = (u16*)(smem + LR_A2);

  float* probO = out;
  float* h1o = out + B;
  float* c1o = out + B + B * 64;
  float* h2o = out + B + B * 128;
  float* c2o = out + B + B * 192;

  const u16* w1 = wbf + WS_W1;    // [256][160]
  const u16* w2 = wbf + WS_W2;    // [256][128]
  const u16* wF = wbf + WS_FC1;   // [32][128] K-remapped

  // ---- staging ----
  for (int i = t; i < 512; i += NT) sw[i] = bc[i];
  for (int i = t; i < 32;  i += NT) sw[LO_FC1B + i] = fc1bg[i];
  for (int i = t; i < 32;  i += NT) sw[LO_FC2W + i] = fc2wg[i];
  if (t == 0) sw[LO_FC2B] = fc2bg[0];
  // feat (bf16) -> A1 cols 0..79
  for (int i = t; i < 640; i += NT) {
    int m = i / 10, o = (i - m * 10) * 8;
    *(uint4*)(A1 + m * A1S + o) = *(const uint4*)(featg + (size_t)(base + m) * 80 + o);
  }
  // h1 fp32 -> A1 cols 80..143
  {
    const float4* hsrc = (const float4*)h1g + (size_t)blk * 1024;
    for (int i = t; i < 1024; i += NT) {
      int m = i >> 4, j4 = (i & 15) * 4;
      *(uint2*)(A1 + m * A1S + 80 + j4) = pack4(hsrc[i]);
    }
  }
  // zero A1 cols 144..159
  for (int i = t; i < 256; i += NT) {
    int m = i >> 2, k4 = 144 + (i & 3) * 4;
    *(uint2*)(A1 + m * A1S + k4) = make_uint2(0u, 0u);
  }
  // h2 fp32 -> A2 cols 64..127
  {
    const float4* hsrc = (const float4*)h2g + (size_t)blk * 1024;
    for (int i = t; i < 1024; i += NT) {
      int m = i >> 4, j4 = (i & 15) * 4;
      *(uint2*)(A2 + m * A2S + 64 + j4) = pack4(hsrc[i]);
    }
  }
  __syncthreads();

  const int w = t >> 6, lane = t & 63, q = lane >> 4, l15 = lane & 15;
  const int j = w * 16 + l15;

  // ---- P7: lstm1, B-frags held in registers, M-loop ----
  {
    bf16x8 bf1[4][5];
#pragma unroll
    for (int g = 0; g < 4; ++g) {
      const u16* row = w1 + (size_t)(g * 64 + j) * 160 + q * 8;
#pragma unroll
      for (int kc = 0; kc < 5; ++kc) bf1[g][kc] = *(const bf16x8*)(row + kc * 32);
    }
    float bI = sw[LO_B1 + j], bF = sw[LO_B1 + 64 + j], bG = sw[LO_B1 + 128 + j], bO = sw[LO_B1 + 192 + j];

#pragma unroll 1
    for (int mt = 0; mt < 4; ++mt) {
      f32x4 acc[4];
#pragma unroll
      for (int g = 0; g < 4; ++g) { acc[g][0]=0.f; acc[g][1]=0.f; acc[g][2]=0.f; acc[g][3]=0.f; }
      const u16* aB = A1 + (mt * 16 + l15) * A1S + q * 8;
#pragma unroll
      for (int kc = 0; kc < 5; ++kc) {
        bf16x8 af = *(const bf16x8*)(aB + kc * 32);
#pragma unroll
        for (int g = 0; g < 4; ++g)
          acc[g] = __builtin_amdgcn_mfma_f32_16x16x32_bf16(af, bf1[g][kc], acc[g], 0, 0, 0);
      }
#pragma unroll
      for (int r = 0; r < 4; ++r) {
        int m = mt * 16 + q * 4 + r;
        int b = base + m;
        float iv = acc[0][r] + bI;
        float fv = acc[1][r] + bF;
        float gv = acc[2][r] + bG;
        float ov = acc[3][r] + bO;
        float cold = c1g[b * 64 + j];
        float cn = sigm(fv) * cold + sigm(iv) * tanh_(gv);
        float hn = sigm(ov) * tanh_(cn);
        c1o[b * 64 + j] = cn;
        h1o[b * 64 + j] = hn;
        A2[m * A2S + j] = f2bu(hn);    // A2 cols 0..63 (not read until P8)
      }
    }
  }
  __syncthreads();

  // ---- P8: lstm2 on A2=[h1new|h2old]; h2new -> A1 cols 0..63 (A1 dead) ----
  {
    bf16x8 bf2[4][4];
#pragma unroll
    for (int g = 0; g < 4; ++g) {
      const u16* row = w2 + (size_t)(g * 64 + j) * 128 + q * 8;
#pragma unroll
      for (int kc = 0; kc < 4; ++kc) bf2[g][kc] = *(const bf16x8*)(row + kc * 32);
    }
    float bI = sw[LO_B2 + j], bF = sw[LO_B2 + 64 + j], bG = sw[LO_B2 + 128 + j], bO = sw[LO_B2 + 192 + j];

#pragma unroll 1
    for (int mt = 0; mt < 4; ++mt) {
      f32x4 acc[4];
#pragma unroll
      for (int g = 0; g < 4; ++g) { acc[g][0]=0.f; acc[g][1]=0.f; acc[g][2]=0.f; acc[g][3]=0.f; }
      const u16* aB = A2 + (mt * 16 + l15) * A2S + q * 8;
#pragma unroll
      for (int kc = 0; kc < 4; ++kc) {
        bf16x8 af = *(const bf16x8*)(aB + kc * 32);
#pragma unroll
        for (int g = 0; g < 4; ++g)
          acc[g] = __builtin_amdgcn_mfma_f32_16x16x32_bf16(af, bf2[g][kc], acc[g], 0, 0, 0);
      }
#pragma unroll
      for (int r = 0; r < 4; ++r) {
        int m = mt * 16 + q * 4 + r;
        int b = base + m;
        float iv = acc[0][r] + bI;
        float fv = acc[1][r] + bF;
        float gv = acc[2][r] + bG;
        float ov = acc[3][r] + bO;
        float cold = c2g[b * 64 + j];
        float cn = sigm(fv) * cold + sigm(iv) * tanh_(gv);
        float hn = sigm(ov) * tanh_(cn);
        c2o[b * 64 + j] = cn;
        h2o[b * 64 + j] = hn;
        A1[m * A1S + j] = f2bu(hn);    // h2new, cols 0..63 of A1 (A1 only read again in fc1 kc>=2)
      }
    }
  }
  __syncthreads();

  // ---- P9: fc1 on z(ours)=[h1new (A2 cols0..63) | h2new (A1 cols0..63)], weights pre-remapped ----
  {
    f32x4 accf[2];
#pragma unroll
    for (int nt = 0; nt < 2; ++nt) { accf[nt][0]=0.f; accf[nt][1]=0.f; accf[nt][2]=0.f; accf[nt][3]=0.f; }
    int m0 = w * 16;
#pragma unroll
    for (int kc = 0; kc < 4; ++kc) {
      bf16x8 a = (kc < 2)
        ? *(const bf16x8*)(A2 + (m0 + l15) * A2S + kc * 32 + q * 8)
        : *(const bf16x8*)(A1 + (m0 + l15) * A1S + (kc - 2) * 32 + q * 8);
#pragma unroll
      for (int nt = 0; nt < 2; ++nt) {
        int n = nt * 16 + l15;
        bf16x8 bfr = *(const bf16x8*)(wF + n * 128 + kc * 32 + q * 8);
        accf[nt] = __builtin_amdgcn_mfma_f32_16x16x32_bf16(a, bfr, accf[nt], 0, 0, 0);
      }
    }
    __syncthreads();   // all fc1 LDS reads done before zz overwrites A1 region
#pragma unroll
    for (int nt = 0; nt < 2; ++nt) {
      int n = nt * 16 + l15;
#pragma unroll
      for (int r = 0; r < 4; ++r) {
        int m = m0 + q * 4 + r;
        zz[m * 33 + n] = fmaxf(accf[nt][r] + sw[LO_FC1B + n], 0.f);
      }
    }
  }
  __syncthreads();

  // ---- P10: fc2 + sigmoid ----
  if (t < 64) {
    int m = t;
    float s = sw[LO_FC2B];
#pragma unroll
    for (int k = 0; k < 32; ++k) s = fmaf(zz[m * 33 + k], sw[LO_FC2W + k], s);
    probO[base + m] = sigm(s);
  }
}

extern "C" void kernel_launch(void* const* d_in, const int* in_sizes, int n_in,
                              void* d_out, int out_size, void* d_ws, size_t ws_size,
                              hipStream_t stream) {
  (void)n_in; (void)out_size; (void)ws_size;
  int B = in_sizes[0] / 123;
  u16* wbf = (u16*)d_ws;
  float* bcm = (float*)((char*)d_ws + WS_BOFF);
  u16* featg = (u16*)d_ws + WS_FEAT_U16;

  hipLaunchKernelGGL(prep, dim3(304), dim3(NT), 0, stream,
      (const float*)d_in[14], (const float*)d_in[15],
      (const float*)d_in[18], (const float*)d_in[19],
      (const float*)d_in[22],
      (const float*)d_in[16], (const float*)d_in[17],
      (const float*)d_in[20], (const float*)d_in[21],
      wbf, bcm);

  hipLaunchKernelGGL(convk, dim3(B / BT), dim3(NT), 0, stream,
      (const float*)d_in[0],
      (const float*)d_in[5], (const float*)d_in[6], (const float*)d_in[7],
      (const float*)d_in[8], (const float*)d_in[9], (const float*)d_in[10],
      (const float*)d_in[11], (const float*)d_in[12], (const float*)d_in[13],
      featg);

  hipLaunchKernelGGL(lstmk, dim3(B / BT), dim3(NT), 0, stream,
      (const float*)d_in[1], (const float*)d_in[2],
      (const float*)d_in[3], (const float*)d_in[4],
      (const float*)d_in[23], (const float*)d_in[24], (const float*)d_in[25],
      wbf, bcm, featg,
      (float*)d_out, B);
}